// Round 6
// baseline (31.528 us; speedup 1.0000x reference)
//
#include <hip/hip_runtime.h>

namespace {
constexpr int kFrame = 80;     // FRAME_SIZE
constexpr int kRad   = 2;      // RADIUS
constexpr int kW     = 5;      // 2*RADIUS+1
constexpr int kB     = 64;
constexpr int kF     = 4000;
constexpr int kN     = kFrame * kF;        // 320000 samples per batch row

constexpr int FPB     = 64;                         // frames per chunk
constexpr int NCHUNK  = (kF + FPB - 1) / FPB;       // 63 chunks per batch
constexpr int CPB     = 4;                          // chunks per block (pipelined)
constexpr int BPB     = (NCHUNK + CPB - 1) / CPB;   // 16 blocks per batch
constexpr int HALO_LO = 304;                        // covers lbase >= 4 (p <= 298)
constexpr int HALO_HI = 84;
constexpr int LN      = FPB * kFrame + HALO_LO + HALO_HI;   // 5508 logical floats
constexpr int LPHYS   = LN + 4 * ((LN + 31) / 32);          // 6200 floats (24.8 KB)
constexpr int NQ      = 6;   // staging quads per thread = ceil(LN/4/256)
}

// Bank-deconflict remap: +4 pad words per 32. Preserves contiguity AND 16B
// alignment of any aligned quad.
__device__ __forceinline__ int phys(int i) { return i + ((i >> 5) << 2); }

template <bool SAFE>
__device__ __forceinline__ void issue_stage(const float* __restrict__ xb, int o,
                                            int tid, float4* r) {
#pragma unroll
    for (int k = 0; k < NQ; ++k) {
        int i4 = (k * 256 + tid) * 4;
        if (i4 < LN) {
            if constexpr (SAFE) {
                r[k] = *reinterpret_cast<const float4*>(xb + o + i4);
            } else {
                int g = o + i4;
                // JAX pad semantics: g<0 -> 0; g>=N -> x[N-1]
                float t0 = (g + 0 >= 0) ? xb[min(g + 0, kN - 1)] : 0.f;
                float t1 = (g + 1 >= 0) ? xb[min(g + 1, kN - 1)] : 0.f;
                float t2 = (g + 2 >= 0) ? xb[min(g + 2, kN - 1)] : 0.f;
                float t3 = (g + 3 >= 0) ? xb[min(g + 3, kN - 1)] : 0.f;
                r[k] = make_float4(t0, t1, t2, t3);
            }
        }
    }
}

__device__ __forceinline__ void write_stage(float* __restrict__ buf, int tid,
                                            const float4* r) {
#pragma unroll
    for (int k = 0; k < NQ; ++k) {
        int i4 = (k * 256 + tid) * 4;
        if (i4 < LN)   // compiler's s_waitcnt on r-use drains the prefetch here
            *reinterpret_cast<float4*>(&buf[phys(i4)]) = r[k];
    }
}

// (256,4): VGPR cap 128. Fully scalarized compute (R5) + 24 prefetch VGPRs.
__global__ __launch_bounds__(256, 4)
void pitch_acorr_kernel(const float* __restrict__ x,
                        const int* __restrict__ periods,
                        float* __restrict__ out) {
    __shared__ float lds[2][LPHYS];   // 49.6 KB double buffer

    const int bid = blockIdx.x;
    const int b   = bid / BPB;
    const int blk = bid - b * BPB;
    const int c0  = blk * CPB;
    const int nc  = min(CPB, NCHUNK - c0);
    const int tid = threadIdx.x;
    const int fl  = tid >> 2;     // local frame
    const int q   = tid & 3;      // quarter: samples [20q, 20q+20)
    const int h   = q * 20;
    const float* xb = x + (long long)b * kN;

    // ---- prologue: stage chunk c0 into buf0 ----
    float4 r[NQ];
    {
        const int f0 = c0 * FPB;
        const int o  = f0 * kFrame - HALO_LO;
        const bool safe = (o >= 0) && (o + LN <= kN);
        if (safe) issue_stage<true >(xb, o, tid, r);
        else      issue_stage<false>(xb, o, tid, r);
    }
    int p = periods[b * kF + min(c0 * FPB + fl, kF - 1)];
    write_stage(lds[0], tid, r);
    __syncthreads();

    for (int c = 0; c < nc; ++c) {
        const int ci = c0 + c;
        const int f0 = ci * FPB;
        const int nf = min(FPB, kF - f0);

        // ---- issue next chunk's loads BEFORE compute (latency hides) ----
        int pn = 0;
        if (c + 1 < nc) {
            const int f0n = (ci + 1) * FPB;
            const int on  = f0n * kFrame - HALO_LO;
            const bool sn = (on >= 0) && (on + LN <= kN);
            if (sn) issue_stage<true >(xb, on, tid, r);
            else    issue_stage<false>(xb, on, tid, r);
            pn = periods[b * kF + min(f0n + fl, kF - 1)];
        }

        // ---- compute chunk ci from lds[c&1] ----
        if (fl < nf) {
            const float* __restrict__ buf = lds[c & 1];
            const int fbase = fl * kFrame + HALO_LO;
            const int lbase = fbase - p - kRad;     // >= 4 always (p <= 298)
            const int s     = lbase & 3;
            const int A0    = lbase - s;
            const int fst   = fbase + h;
            const int gst   = A0 + h;

#define LD4(i) (*reinterpret_cast<const float4*>(&buf[phys(i)]))
            const float4 Ga = LD4(gst +  0), Gb = LD4(gst +  4), Gc = LD4(gst + 8),
                         Gd = LD4(gst + 12), Ge = LD4(gst + 16), Gf = LD4(gst + 20),
                         Gg = LD4(gst + 24);

            const float g0 = Ga.x, g1 = Ga.y, g2 = Ga.z, g3 = Ga.w,
                        g4 = Gb.x, g5 = Gb.y, g6 = Gb.z, g7 = Gb.w,
                        g8 = Gc.x, g9 = Gc.y, g10 = Gc.z, g11 = Gc.w,
                        g12 = Gd.x, g13 = Gd.y, g14 = Gd.z, g15 = Gd.w,
                        g16 = Ge.x, g17 = Ge.y, g18 = Ge.z, g19 = Ge.w,
                        g20 = Gf.x, g21 = Gf.y, g22 = Gf.z, g23 = Gf.w,
                        g24 = Gg.x, g25 = Gg.y, g26 = Gg.z;

            // lag energy E0 + boundary captures first (lets F quads stream)
            const float E0 = g0*g0 + g1*g1 + g2*g2 + g3*g3 + g4*g4 + g5*g5
                           + g6*g6 + g7*g7 + g8*g8 + g9*g9 + g10*g10 + g11*g11
                           + g12*g12 + g13*g13 + g14*g14 + g15*g15 + g16*g16
                           + g17*g17 + g18*g18 + g19*g19;

            float fn = 0.f;
            float D0 = 0.f, D1 = 0.f, D2 = 0.f, D3 = 0.f,
                  D4 = 0.f, D5 = 0.f, D6 = 0.f, D7 = 0.f;

#define STEP(FT, A, B, C, D, E, F, G, H)                                       \
    { const float ft = (FT);                                                   \
      fn += ft * ft;                                                           \
      D0 += ft * (A); D1 += ft * (B); D2 += ft * (C); D3 += ft * (D);          \
      D4 += ft * (E); D5 += ft * (F); D6 += ft * (G); D7 += ft * (H); }

            { const float4 Fa = LD4(fst + 0);
              STEP(Fa.x, g0, g1, g2, g3, g4, g5, g6, g7)
              STEP(Fa.y, g1, g2, g3, g4, g5, g6, g7, g8)
              STEP(Fa.z, g2, g3, g4, g5, g6, g7, g8, g9)
              STEP(Fa.w, g3, g4, g5, g6, g7, g8, g9, g10) }
            { const float4 Fb = LD4(fst + 4);
              STEP(Fb.x, g4, g5, g6, g7, g8, g9, g10, g11)
              STEP(Fb.y, g5, g6, g7, g8, g9, g10, g11, g12)
              STEP(Fb.z, g6, g7, g8, g9, g10, g11, g12, g13)
              STEP(Fb.w, g7, g8, g9, g10, g11, g12, g13, g14) }
            { const float4 Fc = LD4(fst + 8);
              STEP(Fc.x, g8, g9, g10, g11, g12, g13, g14, g15)
              STEP(Fc.y, g9, g10, g11, g12, g13, g14, g15, g16)
              STEP(Fc.z, g10, g11, g12, g13, g14, g15, g16, g17)
              STEP(Fc.w, g11, g12, g13, g14, g15, g16, g17, g18) }
            { const float4 Fd = LD4(fst + 12);
              STEP(Fd.x, g12, g13, g14, g15, g16, g17, g18, g19)
              STEP(Fd.y, g13, g14, g15, g16, g17, g18, g19, g20)
              STEP(Fd.z, g14, g15, g16, g17, g18, g19, g20, g21)
              STEP(Fd.w, g15, g16, g17, g18, g19, g20, g21, g22) }
            { const float4 Fe = LD4(fst + 16);
              STEP(Fe.x, g16, g17, g18, g19, g20, g21, g22, g23)
              STEP(Fe.y, g17, g18, g19, g20, g21, g22, g23, g24)
              STEP(Fe.z, g18, g19, g20, g21, g22, g23, g24, g25)
              STEP(Fe.w, g19, g20, g21, g22, g23, g24, g25, g26) }
#undef STEP
#undef LD4

            const float E1 = E0 + (g20*g20 - g0*g0);
            const float E2 = E1 + (g21*g21 - g1*g1);
            const float E3 = E2 + (g22*g22 - g2*g2);
            const float E4 = E3 + (g23*g23 - g3*g3);
            const float E5 = E4 + (g24*g24 - g4*g4);
            const float E6 = E5 + (g25*g25 - g5*g5);
            const float E7 = E6 + (g26*g26 - g6*g6);

            const bool s1 = (s & 1) != 0, s2 = (s & 2) != 0;
            float d0 = s2 ? (s1 ? D3 : D2) : (s1 ? D1 : D0);
            float d1 = s2 ? (s1 ? D4 : D3) : (s1 ? D2 : D1);
            float d2 = s2 ? (s1 ? D5 : D4) : (s1 ? D3 : D2);
            float d3 = s2 ? (s1 ? D6 : D5) : (s1 ? D4 : D3);
            float d4 = s2 ? (s1 ? D7 : D6) : (s1 ? D5 : D4);
            float e0 = s2 ? (s1 ? E3 : E2) : (s1 ? E1 : E0);
            float e1 = s2 ? (s1 ? E4 : E3) : (s1 ? E2 : E1);
            float e2 = s2 ? (s1 ? E5 : E4) : (s1 ? E3 : E2);
            float e3 = s2 ? (s1 ? E6 : E5) : (s1 ? E4 : E3);
            float e4 = s2 ? (s1 ? E7 : E6) : (s1 ? E5 : E4);

            float fns = fn;
            fns += __shfl_xor(fns, 1); fns += __shfl_xor(fns, 2);
            d0 += __shfl_xor(d0, 1); d0 += __shfl_xor(d0, 2);
            d1 += __shfl_xor(d1, 1); d1 += __shfl_xor(d1, 2);
            d2 += __shfl_xor(d2, 1); d2 += __shfl_xor(d2, 2);
            d3 += __shfl_xor(d3, 1); d3 += __shfl_xor(d3, 2);
            d4 += __shfl_xor(d4, 1); d4 += __shfl_xor(d4, 2);
            e0 += __shfl_xor(e0, 1); e0 += __shfl_xor(e0, 2);
            e1 += __shfl_xor(e1, 1); e1 += __shfl_xor(e1, 2);
            e2 += __shfl_xor(e2, 1); e2 += __shfl_xor(e2, 2);
            e3 += __shfl_xor(e3, 1); e3 += __shfl_xor(e3, 2);
            e4 += __shfl_xor(e4, 1); e4 += __shfl_xor(e4, 2);

            if (q == 0) {
                float* op = out + (long long)(b * kF + f0 + fl) * kW;
                op[0] = d0 * rsqrtf(fns * e0 + 1e-9f);
                op[1] = d1 * rsqrtf(fns * e1 + 1e-9f);
                op[2] = d2 * rsqrtf(fns * e2 + 1e-9f);
                op[3] = d3 * rsqrtf(fns * e3 + 1e-9f);
                op[4] = d4 * rsqrtf(fns * e4 + 1e-9f);
            }
        }

        __syncthreads();   // readers of lds[(c+1)&1] (iter c-1) are done
        if (c + 1 < nc) write_stage(lds[(c + 1) & 1], tid, r);
        __syncthreads();   // writes visible before next compute
        p = pn;
    }
}

extern "C" void kernel_launch(void* const* d_in, const int* in_sizes, int n_in,
                              void* d_out, int out_size, void* d_ws, size_t ws_size,
                              hipStream_t stream) {
    const float* x       = (const float*)d_in[0];
    const int*   periods = (const int*)d_in[1];
    float*       out     = (float*)d_out;

    const int grid = kB * BPB;   // 1024 persistent-ish blocks, 4 chunks each
    pitch_acorr_kernel<<<grid, 256, 0, stream>>>(x, periods, out);
}

// Round 7
// 21.400 us; speedup vs baseline: 1.4733x; 1.4733x over previous
//
#include <hip/hip_runtime.h>

namespace {
constexpr int kFrame = 80;     // FRAME_SIZE
constexpr int kRad   = 2;      // RADIUS
constexpr int kW     = 5;      // 2*RADIUS+1
constexpr int kB     = 64;
constexpr int kF     = 4000;
constexpr int kN     = kFrame * kF;        // 320000 samples per batch row

constexpr int FPB     = 64;                // frames per block (4 threads/frame)
constexpr int BPB     = (kF + FPB - 1) / FPB;  // 63 blocks per batch
constexpr int HALO_LO = 304;               // covers lbase >= 4 (p <= 298); mult of 16
constexpr int HALO_HI = 84;
constexpr int LN      = FPB * kFrame + HALO_LO + HALO_HI;   // 5508 logical floats
constexpr int LPHYS   = LN + 4 * ((LN + 31) / 32);          // 6200 floats (24.8 KB)
constexpr int NQ      = 6;   // staging quads per thread = ceil(LN/4/256)
}

// Bank-deconflict remap: +4 pad words per 32. Preserves contiguity AND 16B
// alignment of any aligned quad.
__device__ __forceinline__ int phys(int i) { return i + ((i >> 5) << 2); }

// Issue ALL global loads first (back-to-back, one vmcnt ramp), write LDS later.
// R5's fused load+ds_write per quad serialized the 6 HBM loads (~900cyc each).
template <bool SAFE>
__device__ __forceinline__ void issue_stage(const float* __restrict__ xb, int o,
                                            int tid, float4* r) {
#pragma unroll
    for (int k = 0; k < NQ; ++k) {
        int i4 = (k * 256 + tid) * 4;
        if (i4 < LN) {
            if constexpr (SAFE) {
                r[k] = *reinterpret_cast<const float4*>(xb + o + i4);
            } else {
                int g = o + i4;
                // JAX pad semantics: g<0 -> 0; g>=N -> x[N-1]
                float t0 = (g + 0 >= 0) ? xb[min(g + 0, kN - 1)] : 0.f;
                float t1 = (g + 1 >= 0) ? xb[min(g + 1, kN - 1)] : 0.f;
                float t2 = (g + 2 >= 0) ? xb[min(g + 2, kN - 1)] : 0.f;
                float t3 = (g + 3 >= 0) ? xb[min(g + 3, kN - 1)] : 0.f;
                r[k] = make_float4(t0, t1, t2, t3);
            }
        }
    }
}

__device__ __forceinline__ void write_stage(float* __restrict__ buf, int tid,
                                            const float4* r) {
#pragma unroll
    for (int k = 0; k < NQ; ++k) {
        int i4 = (k * 256 + tid) * 4;
        if (i4 < LN)
            *reinterpret_cast<float4*>(&buf[phys(i4)]) = r[k];
    }
}

// (256,4): VGPR cap 128; fully scalarized so nothing can be memory-homed.
__global__ __launch_bounds__(256, 4)
void pitch_acorr_kernel(const float* __restrict__ x,
                        const int* __restrict__ periods,
                        float* __restrict__ out) {
    __shared__ float lds[LPHYS];

    const int bid = blockIdx.x;
    const int b   = bid / BPB;
    const int blk = bid - b * BPB;
    const int f0  = blk * FPB;
    const int nf  = min(FPB, kF - f0);
    const int tid = threadIdx.x;
    const int fl  = tid >> 2;     // local frame
    const int q   = tid & 3;      // quarter: samples [20q, 20q+20)
    const int h   = q * 20;
    const float* xb = x + (long long)b * kN;
    const int o = f0 * kFrame - HALO_LO;   // global idx of lds logical 0

    // Prefetch period; its latency hides under the staging loads.
    const int p = periods[b * kF + min(f0 + fl, kF - 1)];

    float4 r[NQ];
    const bool safe = (o >= 0) && (o + LN <= kN);   // block-uniform
    if (safe) issue_stage<true >(xb, o, tid, r);
    else      issue_stage<false>(xb, o, tid, r);
    write_stage(lds, tid, r);
    __syncthreads();

    if (fl >= nf) return;        // no barriers below

    const int fbase = fl * kFrame + HALO_LO;   // logical idx of frame start
    const int lbase = fbase - p - kRad;        // >= 4 always (p <= 298)
    const int s     = lbase & 3;               // quad misalignment, 0..3
    const int A0    = lbase - s;               // 16B-aligned lag base
    const int fst   = fbase + h;
    const int gst   = A0 + h;

#define LD4(i) (*reinterpret_cast<const float4*>(&lds[phys(i)]))
    const float4 Ga = LD4(gst +  0), Gb = LD4(gst +  4), Gc = LD4(gst +  8),
                 Gd = LD4(gst + 12), Ge = LD4(gst + 16), Gf = LD4(gst + 20),
                 Gg = LD4(gst + 24);

    const float g0 = Ga.x, g1 = Ga.y, g2 = Ga.z, g3 = Ga.w,
                g4 = Gb.x, g5 = Gb.y, g6 = Gb.z, g7 = Gb.w,
                g8 = Gc.x, g9 = Gc.y, g10 = Gc.z, g11 = Gc.w,
                g12 = Gd.x, g13 = Gd.y, g14 = Gd.z, g15 = Gd.w,
                g16 = Ge.x, g17 = Ge.y, g18 = Ge.z, g19 = Ge.w,
                g20 = Gf.x, g21 = Gf.y, g22 = Gf.z, g23 = Gf.w,
                g24 = Gg.x, g25 = Gg.y, g26 = Gg.z;

    const float E0 = g0*g0 + g1*g1 + g2*g2 + g3*g3 + g4*g4 + g5*g5 + g6*g6
                   + g7*g7 + g8*g8 + g9*g9 + g10*g10 + g11*g11 + g12*g12
                   + g13*g13 + g14*g14 + g15*g15 + g16*g16 + g17*g17 + g18*g18
                   + g19*g19;

    float fn = 0.f;
    float D0 = 0.f, D1 = 0.f, D2 = 0.f, D3 = 0.f,
          D4 = 0.f, D5 = 0.f, D6 = 0.f, D7 = 0.f;

#define STEP(FT, A, B, C, D, E, F, G, H)                                       \
    { const float ft = (FT);                                                   \
      fn += ft * ft;                                                           \
      D0 += ft * (A); D1 += ft * (B); D2 += ft * (C); D3 += ft * (D);          \
      D4 += ft * (E); D5 += ft * (F); D6 += ft * (G); D7 += ft * (H); }

    { const float4 Fa = LD4(fst + 0);
      STEP(Fa.x, g0, g1, g2, g3, g4, g5, g6, g7)
      STEP(Fa.y, g1, g2, g3, g4, g5, g6, g7, g8)
      STEP(Fa.z, g2, g3, g4, g5, g6, g7, g8, g9)
      STEP(Fa.w, g3, g4, g5, g6, g7, g8, g9, g10) }
    { const float4 Fb = LD4(fst + 4);
      STEP(Fb.x, g4, g5, g6, g7, g8, g9, g10, g11)
      STEP(Fb.y, g5, g6, g7, g8, g9, g10, g11, g12)
      STEP(Fb.z, g6, g7, g8, g9, g10, g11, g12, g13)
      STEP(Fb.w, g7, g8, g9, g10, g11, g12, g13, g14) }
    { const float4 Fc = LD4(fst + 8);
      STEP(Fc.x, g8, g9, g10, g11, g12, g13, g14, g15)
      STEP(Fc.y, g9, g10, g11, g12, g13, g14, g15, g16)
      STEP(Fc.z, g10, g11, g12, g13, g14, g15, g16, g17)
      STEP(Fc.w, g11, g12, g13, g14, g15, g16, g17, g18) }
    { const float4 Fd = LD4(fst + 12);
      STEP(Fd.x, g12, g13, g14, g15, g16, g17, g18, g19)
      STEP(Fd.y, g13, g14, g15, g16, g17, g18, g19, g20)
      STEP(Fd.z, g14, g15, g16, g17, g18, g19, g20, g21)
      STEP(Fd.w, g15, g16, g17, g18, g19, g20, g21, g22) }
    { const float4 Fe = LD4(fst + 16);
      STEP(Fe.x, g16, g17, g18, g19, g20, g21, g22, g23)
      STEP(Fe.y, g17, g18, g19, g20, g21, g22, g23, g24)
      STEP(Fe.z, g18, g19, g20, g21, g22, g23, g24, g25)
      STEP(Fe.w, g19, g20, g21, g22, g23, g24, g25, g26) }
#undef STEP
#undef LD4

    const float E1 = E0 + (g20*g20 - g0*g0);
    const float E2 = E1 + (g21*g21 - g1*g1);
    const float E3 = E2 + (g22*g22 - g2*g2);
    const float E4 = E3 + (g23*g23 - g3*g3);
    const float E5 = E4 + (g24*g24 - g4*g4);
    const float E6 = E5 + (g25*g25 - g5*g5);
    const float E7 = E6 + (g26*g26 - g6*g6);

    // d_k = D_{k+s}, e_k = E_{k+s}
    const bool s1 = (s & 1) != 0, s2 = (s & 2) != 0;
    float d0 = s2 ? (s1 ? D3 : D2) : (s1 ? D1 : D0);
    float d1 = s2 ? (s1 ? D4 : D3) : (s1 ? D2 : D1);
    float d2 = s2 ? (s1 ? D5 : D4) : (s1 ? D3 : D2);
    float d3 = s2 ? (s1 ? D6 : D5) : (s1 ? D4 : D3);
    float d4 = s2 ? (s1 ? D7 : D6) : (s1 ? D5 : D4);
    float e0 = s2 ? (s1 ? E3 : E2) : (s1 ? E1 : E0);
    float e1 = s2 ? (s1 ? E4 : E3) : (s1 ? E2 : E1);
    float e2 = s2 ? (s1 ? E5 : E4) : (s1 ? E3 : E2);
    float e3 = s2 ? (s1 ? E6 : E5) : (s1 ? E4 : E3);
    float e4 = s2 ? (s1 ? E7 : E6) : (s1 ? E5 : E4);

    // butterfly-reduce over the 4 quarter-threads of this frame
    fn += __shfl_xor(fn, 1); fn += __shfl_xor(fn, 2);
    d0 += __shfl_xor(d0, 1); d0 += __shfl_xor(d0, 2);
    d1 += __shfl_xor(d1, 1); d1 += __shfl_xor(d1, 2);
    d2 += __shfl_xor(d2, 1); d2 += __shfl_xor(d2, 2);
    d3 += __shfl_xor(d3, 1); d3 += __shfl_xor(d3, 2);
    d4 += __shfl_xor(d4, 1); d4 += __shfl_xor(d4, 2);
    e0 += __shfl_xor(e0, 1); e0 += __shfl_xor(e0, 2);
    e1 += __shfl_xor(e1, 1); e1 += __shfl_xor(e1, 2);
    e2 += __shfl_xor(e2, 1); e2 += __shfl_xor(e2, 2);
    e3 += __shfl_xor(e3, 1); e3 += __shfl_xor(e3, 2);
    e4 += __shfl_xor(e4, 1); e4 += __shfl_xor(e4, 2);

    // Distributed store: lane q writes op[q]; lane 0 also op[4].
    // Values are replicated across the 4 lanes after the butterfly.
    float* op = out + (long long)(b * kF + f0 + fl) * kW;
    const float dq = (q & 2) ? ((q & 1) ? d3 : d2) : ((q & 1) ? d1 : d0);
    const float eq = (q & 2) ? ((q & 1) ? e3 : e2) : ((q & 1) ? e1 : e0);
    op[q] = dq * rsqrtf(fn * eq + 1e-9f);
    if (q == 0) op[4] = d4 * rsqrtf(fn * e4 + 1e-9f);
}

extern "C" void kernel_launch(void* const* d_in, const int* in_sizes, int n_in,
                              void* d_out, int out_size, void* d_ws, size_t ws_size,
                              hipStream_t stream) {
    const float* x       = (const float*)d_in[0];
    const int*   periods = (const int*)d_in[1];
    float*       out     = (float*)d_out;

    const int grid = kB * BPB;   // 4032 blocks, one per (batch, 64-frame chunk)
    pitch_acorr_kernel<<<grid, 256, 0, stream>>>(x, periods, out);
}